// Round 19
// baseline (146.894 us; speedup 1.0000x reference)
//
#include <hip/hip_runtime.h>

#define N_NODES 100000
#define N_EDGES 1600000
#define IN_F 256
#define OUT_F 128

#define NBUCK 1563           // ceil(N_NODES / 64): bucket = dst >> 6
#define FBUCK 64             // nodes per bucket
#define CAP 1664             // slots per bucket region (mean 1024, 20 sigma)

#define SORT_CHUNKS 128
#define CHUNK_E (N_EDGES / SORT_CHUNKS)  // 12500

#define GEMM_BM 128
#define GEMM_BLOCKS ((N_NODES + GEMM_BM - 1) / GEMM_BM)   // 782

typedef __attribute__((ext_vector_type(8))) short bf16x8;
typedef __attribute__((ext_vector_type(4))) float f32x4;

__device__ __forceinline__ unsigned short f2bf(float f) {
    unsigned u = __float_as_uint(f);
    unsigned r = u + 0x7fffu + ((u >> 16) & 1u);  // RNE
    return (unsigned short)(r >> 16);
}

// ---------------------------------------------------------------------------
// K1: wtrans (blocks 0..127) + zero cursor (blocks 128..134)
// ---------------------------------------------------------------------------
__global__ __launch_bounds__(256) void wz_kernel(const float* __restrict__ w,
                                                 unsigned short* __restrict__ wt,
                                                 int* __restrict__ cursor) {
    const int tid = threadIdx.x;
    if (blockIdx.x < 128) {
        int c = blockIdx.x;
        wt[c * IN_F + tid] = f2bf(w[tid * OUT_F + c]);
    } else {
        int i = (blockIdx.x - 128) * 256 + tid;
        if (i < NBUCK) cursor[i] = 0;
    }
}

// ---------------------------------------------------------------------------
// K2: sort (blocks 0..127)  ∥  gemm (blocks 128..909), 512 threads.
// (R16 proven structure — best result 115.4 µs.)
// All stream-once inputs (x, rowi, coli, val) read NONTEMPORAL so the
// 25.6 MB support array — re-read 16x by K3's gather — stays L2/L3 resident.
// ---------------------------------------------------------------------------
__global__ __launch_bounds__(512, 4) void gemm_sort_kernel(const float* __restrict__ x,
                                                           const unsigned short* __restrict__ wt,
                                                           unsigned short* __restrict__ support,
                                                           const int* __restrict__ rowi,
                                                           const int* __restrict__ coli,
                                                           const float* __restrict__ val,
                                                           int* __restrict__ cursor,
                                                           uint2* __restrict__ tmp) {
    __shared__ unsigned short ws[128 * 256];  // 64 KB (gemm path)
    __shared__ int bh[NBUCK];                 // 6.3 KB (sort path)

    const int tid = threadIdx.x;

    if (blockIdx.x < SORT_CHUNKS) {
        // ----- sort chunk -----
        const int c = blockIdx.x;
        for (int i = tid; i < NBUCK; i += 512) bh[i] = 0;
        __syncthreads();
        const int e0 = c * CHUNK_E;
        for (int i = tid; i < CHUNK_E; i += 512)
            atomicAdd(&bh[__builtin_nontemporal_load(&rowi[e0 + i]) >> 6], 1);
        __syncthreads();
        for (int i = tid; i < NBUCK; i += 512) {
            int n = bh[i];
            bh[i] = n ? atomicAdd(&cursor[i], n) : 0;
        }
        __syncthreads();
        for (int i = tid; i < CHUNK_E; i += 512) {
            int e = e0 + i;
            int dst = __builtin_nontemporal_load(&rowi[e]);
            int b = dst >> 6;
            int pos = atomicAdd(&bh[b], 1);
            unsigned cv = (unsigned)__builtin_nontemporal_load(&coli[e]);
            float vv = __builtin_nontemporal_load(&val[e]);
            tmp[(size_t)b * CAP + pos] =
                make_uint2(((unsigned)(dst & 63) << 17) | cv, __float_as_uint(vv));
        }
        return;
    }

    // ----- gemm -----
    const int lane = tid & 63;
    const int wv = tid >> 6;
    const int row0 = (blockIdx.x - SORT_CHUNKS) * GEMM_BM;
    const int l15 = lane & 15;
    const int kq = lane >> 4;

#pragma unroll
    for (int it = 0; it < 8; ++it) {
        int ci = it * 512 + tid;
        int col = ci >> 5, ch = ci & 31;
        uint4 v = *reinterpret_cast<const uint4*>(&wt[col * IN_F + ch * 8]);
        int slot = ch ^ (col & 7);
        *reinterpret_cast<uint4*>(&ws[col * 256 + slot * 8]) = v;
    }
    __syncthreads();  // the ONLY barrier

    int arow = row0 + wv * 16 + l15;
    if (arow > N_NODES - 1) arow = N_NODES - 1;
    const float* xrow = &x[(size_t)arow * IN_F + kq * 8];

    f32x4 acc[8];
#pragma unroll
    for (int n = 0; n < 8; ++n) acc[n] = (f32x4){0.f, 0.f, 0.f, 0.f};

#pragma unroll
    for (int kt = 0; kt < 8; ++kt) {
        f32x4 a0 = __builtin_nontemporal_load(reinterpret_cast<const f32x4*>(xrow + kt * 32));
        f32x4 a1 = __builtin_nontemporal_load(reinterpret_cast<const f32x4*>(xrow + kt * 32 + 4));
        bf16x8 af;
        af[0] = (short)f2bf(a0[0]); af[1] = (short)f2bf(a0[1]);
        af[2] = (short)f2bf(a0[2]); af[3] = (short)f2bf(a0[3]);
        af[4] = (short)f2bf(a1[0]); af[5] = (short)f2bf(a1[1]);
        af[6] = (short)f2bf(a1[2]); af[7] = (short)f2bf(a1[3]);
#pragma unroll
        for (int n = 0; n < 8; ++n) {
            int col = n * 16 + l15;
            int slot = (kt * 4 + kq) ^ (col & 7);
            bf16x8 bfv = *reinterpret_cast<const bf16x8*>(&ws[col * 256 + slot * 8]);
            acc[n] = __builtin_amdgcn_mfma_f32_16x16x32_bf16(af, bfv, acc[n], 0, 0, 0);
        }
    }

#pragma unroll
    for (int r = 0; r < 4; ++r) {
        int row = row0 + wv * 16 + kq * 4 + r;
        if (row < N_NODES) {
#pragma unroll
            for (int n = 0; n < 8; ++n) {
                support[(size_t)row * OUT_F + n * 16 + l15] = f2bf(acc[n][r]);
            }
        }
    }
}

// ---------------------------------------------------------------------------
// K3: fused fine-sort + accumulate, one block per 64-node bucket.
// tmp reads nontemporal (streamed once); support gathers use normal cached
// loads (the whole point: support should be L2/L3-hot now).
// ---------------------------------------------------------------------------
__global__ __launch_bounds__(256) void fine_accum_kernel(const unsigned short* __restrict__ support,
                                                         const uint2* __restrict__ tmp,
                                                         const int* __restrict__ cursor,
                                                         const float* __restrict__ bias,
                                                         float* __restrict__ out) {
    __shared__ uint2 plds[CAP];    // 13.3 KB sorted pairs
    __shared__ int hist[FBUCK];
    __shared__ int scanb[FBUCK];
    __shared__ int cur[FBUCK];

    const int tid = threadIdx.x, b = blockIdx.x;
    const int cnt = cursor[b];
    const size_t base = (size_t)b * CAP;

    if (tid < FBUCK) hist[tid] = 0;
    __syncthreads();
    for (int i = tid; i < cnt; i += 256) {
        unsigned long long uu = __builtin_nontemporal_load(
            reinterpret_cast<const unsigned long long*>(&tmp[base + i]));
        atomicAdd(&hist[(unsigned)(uu & 0xffffffffu) >> 17], 1);
    }
    __syncthreads();
    if (tid < FBUCK) scanb[tid] = hist[tid];
    __syncthreads();
#pragma unroll
    for (int off = 1; off < FBUCK; off <<= 1) {
        int t = (tid < FBUCK && tid >= off) ? scanb[tid - off] : 0;
        __syncthreads();
        if (tid < FBUCK) scanb[tid] += t;
        __syncthreads();
    }
    if (tid < FBUCK) cur[tid] = scanb[tid] - hist[tid];  // exclusive starts
    __syncthreads();
    for (int i = tid; i < cnt; i += 256) {
        unsigned long long uu = __builtin_nontemporal_load(
            reinterpret_cast<const unsigned long long*>(&tmp[base + i]));
        unsigned ux = (unsigned)(uu & 0xffffffffu);
        int dl = ux >> 17;
        int pos = atomicAdd(&cur[dl], 1);
        plds[pos] = make_uint2(ux & 0x1FFFFu, (unsigned)(uu >> 32));
    }
    __syncthreads();

    // accum: 4 waves x 16 nodes each
    const int lane = tid & 63;
    const int wv = tid >> 6;
    const int grp = lane >> 4;   // edge slot 0..3
    const int l16 = lane & 15;   // feats l16*8 .. +7

    float4 b0 = *reinterpret_cast<const float4*>(&bias[l16 * 8]);
    float4 b1 = *reinterpret_cast<const float4*>(&bias[l16 * 8 + 4]);

    for (int ni = 0; ni < 16; ++ni) {
        const int dl = wv * 16 + ni;
        const int node = b * FBUCK + dl;
        if (node >= N_NODES) break;
        const int s = (dl == 0) ? 0 : scanb[dl - 1];
        const int e = scanb[dl];

        float acc[8];
#pragma unroll
        for (int t = 0; t < 8; ++t) acc[t] = 0.f;

        int j = s + grp;
        for (; j + 4 < e; j += 8) {
            uint2 p0 = plds[j];
            uint2 p1 = plds[j + 4];
            uint4 s0 = *reinterpret_cast<const uint4*>(&support[(size_t)p0.x * OUT_F + l16 * 8]);
            uint4 s1 = *reinterpret_cast<const uint4*>(&support[(size_t)p1.x * OUT_F + l16 * 8]);
            float v0 = __uint_as_float(p0.y);
            float v1 = __uint_as_float(p1.y);
            unsigned u0[4] = {s0.x, s0.y, s0.z, s0.w};
            unsigned u1[4] = {s1.x, s1.y, s1.z, s1.w};
#pragma unroll
            for (int q = 0; q < 4; ++q) {
                acc[2 * q + 0] += __uint_as_float(u0[q] << 16) * v0;
                acc[2 * q + 1] += __uint_as_float(u0[q] & 0xffff0000u) * v0;
                acc[2 * q + 0] += __uint_as_float(u1[q] << 16) * v1;
                acc[2 * q + 1] += __uint_as_float(u1[q] & 0xffff0000u) * v1;
            }
        }
        for (; j < e; j += 4) {
            uint2 p0 = plds[j];
            uint4 s0 = *reinterpret_cast<const uint4*>(&support[(size_t)p0.x * OUT_F + l16 * 8]);
            float v0 = __uint_as_float(p0.y);
            unsigned u0[4] = {s0.x, s0.y, s0.z, s0.w};
#pragma unroll
            for (int q = 0; q < 4; ++q) {
                acc[2 * q + 0] += __uint_as_float(u0[q] << 16) * v0;
                acc[2 * q + 1] += __uint_as_float(u0[q] & 0xffff0000u) * v0;
            }
        }

#pragma unroll
        for (int t = 0; t < 8; ++t) {
            acc[t] += __shfl_xor(acc[t], 16);
            acc[t] += __shfl_xor(acc[t], 32);
        }

        if (grp == 0) {
            f32x4 o0 = {acc[0] + b0.x, acc[1] + b0.y, acc[2] + b0.z, acc[3] + b0.w};
            f32x4 o1 = {acc[4] + b1.x, acc[5] + b1.y, acc[6] + b1.z, acc[7] + b1.w};
            f32x4* op = reinterpret_cast<f32x4*>(&out[(size_t)node * OUT_F + l16 * 8]);
            __builtin_nontemporal_store(o0, op);
            __builtin_nontemporal_store(o1, op + 1);
        }
    }
}

extern "C" void kernel_launch(void* const* d_in, const int* in_sizes, int n_in,
                              void* d_out, int out_size, void* d_ws, size_t ws_size,
                              hipStream_t stream) {
    const float* x       = (const float*)d_in[0];
    const float* weight  = (const float*)d_in[1];
    const float* bias    = (const float*)d_in[2];
    const float* adj_val = (const float*)d_in[3];
    const int*   adj_row = (const int*)d_in[4];
    const int*   adj_col = (const int*)d_in[5];
    float* out = (float*)d_out;

    unsigned short* support = (unsigned short*)d_ws;
    unsigned short* wt = support + (size_t)N_NODES * OUT_F;
    int* cursor = (int*)(wt + IN_F * OUT_F);
    uint2* tmp = (uint2*)(cursor + 1564);

    // K1: weight transpose + zero bucket cursors
    wz_kernel<<<128 + 7, 256, 0, stream>>>(weight, wt, cursor);
    // K2: sort ∥ gemm (R16 structure, nontemporal streaming inputs)
    gemm_sort_kernel<<<SORT_CHUNKS + GEMM_BLOCKS, 512, 0, stream>>>(
        x, wt, support, adj_row, adj_col, adj_val, cursor, tmp);
    // K3: fused fine-sort + accumulate per 64-node bucket
    fine_accum_kernel<<<NBUCK, 256, 0, stream>>>(support, tmp, cursor, bias, out);
}

// Round 20
// 116.052 us; speedup vs baseline: 1.2658x; 1.2658x over previous
//
#include <hip/hip_runtime.h>

#define N_NODES 100000
#define N_EDGES 1600000
#define IN_F 256
#define OUT_F 128

#define NBUCK 1563           // ceil(N_NODES / 64): bucket = dst >> 6
#define FBUCK 64             // nodes per bucket
#define CAP 1664             // slots per bucket region (mean 1024, 20 sigma)

#define SORT_CHUNKS 128
#define CHUNK_E (N_EDGES / SORT_CHUNKS)  // 12500

#define GEMM_BM 128
#define GEMM_BLOCKS ((N_NODES + GEMM_BM - 1) / GEMM_BM)   // 782

typedef __attribute__((ext_vector_type(8))) short bf16x8;
typedef __attribute__((ext_vector_type(4))) float f32x4;

__device__ __forceinline__ unsigned short f2bf(float f) {
    unsigned u = __float_as_uint(f);
    unsigned r = u + 0x7fffu + ((u >> 16) & 1u);  // RNE
    return (unsigned short)(r >> 16);
}

// ---------------------------------------------------------------------------
// K1: wtrans (blocks 0..127) + zero cursor (blocks 128..134)
// ---------------------------------------------------------------------------
__global__ __launch_bounds__(256) void wz_kernel(const float* __restrict__ w,
                                                 unsigned short* __restrict__ wt,
                                                 int* __restrict__ cursor) {
    const int tid = threadIdx.x;
    if (blockIdx.x < 128) {
        int c = blockIdx.x;
        wt[c * IN_F + tid] = f2bf(w[tid * OUT_F + c]);
    } else {
        int i = (blockIdx.x - 128) * 256 + tid;
        if (i < NBUCK) cursor[i] = 0;
    }
}

// ---------------------------------------------------------------------------
// K2: sort (blocks 0..127)  ∥  gemm (blocks 128..909), 512 threads.
//
// sort: per-chunk LDS histogram -> one global atomicAdd per (chunk,bucket)
// reserves a contiguous range in tmp[b*CAP ..] -> direct scatter.
//
// gemm: BM=128, 8 waves; wt (64 KB, whole K=256) resident in LDS,
// XOR-swizzled; barrier-free k-loop. Plain cached loads throughout —
// nontemporal hints measured -31 us (R19), asm hoist null (R17),
// DMA staging null (R12), occupancy scaling null (R11).
// ---------------------------------------------------------------------------
__global__ __launch_bounds__(512, 4) void gemm_sort_kernel(const float* __restrict__ x,
                                                           const unsigned short* __restrict__ wt,
                                                           unsigned short* __restrict__ support,
                                                           const int* __restrict__ rowi,
                                                           const int* __restrict__ coli,
                                                           const float* __restrict__ val,
                                                           int* __restrict__ cursor,
                                                           uint2* __restrict__ tmp) {
    __shared__ unsigned short ws[128 * 256];  // 64 KB (gemm path)
    __shared__ int bh[NBUCK];                 // 6.3 KB (sort path)

    const int tid = threadIdx.x;

    if (blockIdx.x < SORT_CHUNKS) {
        // ----- sort chunk -----
        const int c = blockIdx.x;
        for (int i = tid; i < NBUCK; i += 512) bh[i] = 0;
        __syncthreads();
        const int e0 = c * CHUNK_E;
        for (int i = tid; i < CHUNK_E; i += 512)
            atomicAdd(&bh[rowi[e0 + i] >> 6], 1);
        __syncthreads();
        for (int i = tid; i < NBUCK; i += 512) {
            int n = bh[i];
            bh[i] = n ? atomicAdd(&cursor[i], n) : 0;
        }
        __syncthreads();
        for (int i = tid; i < CHUNK_E; i += 512) {
            int e = e0 + i;
            int dst = rowi[e];
            int b = dst >> 6;
            int pos = atomicAdd(&bh[b], 1);
            tmp[(size_t)b * CAP + pos] =
                make_uint2(((unsigned)(dst & 63) << 17) | (unsigned)coli[e],
                           __float_as_uint(val[e]));
        }
        return;
    }

    // ----- gemm -----
    const int lane = tid & 63;
    const int wv = tid >> 6;
    const int row0 = (blockIdx.x - SORT_CHUNKS) * GEMM_BM;
    const int l15 = lane & 15;
    const int kq = lane >> 4;

#pragma unroll
    for (int it = 0; it < 8; ++it) {
        int ci = it * 512 + tid;
        int col = ci >> 5, ch = ci & 31;
        uint4 v = *reinterpret_cast<const uint4*>(&wt[col * IN_F + ch * 8]);
        int slot = ch ^ (col & 7);
        *reinterpret_cast<uint4*>(&ws[col * 256 + slot * 8]) = v;
    }
    __syncthreads();  // the ONLY barrier

    int arow = row0 + wv * 16 + l15;
    if (arow > N_NODES - 1) arow = N_NODES - 1;
    const float* xrow = &x[(size_t)arow * IN_F + kq * 8];

    f32x4 acc[8];
#pragma unroll
    for (int n = 0; n < 8; ++n) acc[n] = (f32x4){0.f, 0.f, 0.f, 0.f};

#pragma unroll
    for (int kt = 0; kt < 8; ++kt) {
        f32x4 a0 = *reinterpret_cast<const f32x4*>(xrow + kt * 32);
        f32x4 a1 = *reinterpret_cast<const f32x4*>(xrow + kt * 32 + 4);
        bf16x8 af;
        af[0] = (short)f2bf(a0[0]); af[1] = (short)f2bf(a0[1]);
        af[2] = (short)f2bf(a0[2]); af[3] = (short)f2bf(a0[3]);
        af[4] = (short)f2bf(a1[0]); af[5] = (short)f2bf(a1[1]);
        af[6] = (short)f2bf(a1[2]); af[7] = (short)f2bf(a1[3]);
#pragma unroll
        for (int n = 0; n < 8; ++n) {
            int col = n * 16 + l15;
            int slot = (kt * 4 + kq) ^ (col & 7);
            bf16x8 bfv = *reinterpret_cast<const bf16x8*>(&ws[col * 256 + slot * 8]);
            acc[n] = __builtin_amdgcn_mfma_f32_16x16x32_bf16(af, bfv, acc[n], 0, 0, 0);
        }
    }

#pragma unroll
    for (int r = 0; r < 4; ++r) {
        int row = row0 + wv * 16 + kq * 4 + r;
        if (row < N_NODES) {
#pragma unroll
            for (int n = 0; n < 8; ++n) {
                support[(size_t)row * OUT_F + n * 16 + l15] = f2bf(acc[n][r]);
            }
        }
    }
}

// ---------------------------------------------------------------------------
// K3: fused fine-sort + accumulate, one block per 64-node bucket.
// Plain cached loads (R16 proven — nt variants regressed).
// ---------------------------------------------------------------------------
__global__ __launch_bounds__(256) void fine_accum_kernel(const unsigned short* __restrict__ support,
                                                         const uint2* __restrict__ tmp,
                                                         const int* __restrict__ cursor,
                                                         const float* __restrict__ bias,
                                                         float* __restrict__ out) {
    __shared__ uint2 plds[CAP];    // 13.3 KB sorted pairs
    __shared__ int hist[FBUCK];
    __shared__ int scanb[FBUCK];
    __shared__ int cur[FBUCK];

    const int tid = threadIdx.x, b = blockIdx.x;
    const int cnt = cursor[b];
    const size_t base = (size_t)b * CAP;

    if (tid < FBUCK) hist[tid] = 0;
    __syncthreads();
    for (int i = tid; i < cnt; i += 256)
        atomicAdd(&hist[tmp[base + i].x >> 17], 1);
    __syncthreads();
    if (tid < FBUCK) scanb[tid] = hist[tid];
    __syncthreads();
#pragma unroll
    for (int off = 1; off < FBUCK; off <<= 1) {
        int t = (tid < FBUCK && tid >= off) ? scanb[tid - off] : 0;
        __syncthreads();
        if (tid < FBUCK) scanb[tid] += t;
        __syncthreads();
    }
    if (tid < FBUCK) cur[tid] = scanb[tid] - hist[tid];  // exclusive starts
    __syncthreads();
    for (int i = tid; i < cnt; i += 256) {
        uint2 u = tmp[base + i];
        int dl = u.x >> 17;
        int pos = atomicAdd(&cur[dl], 1);
        plds[pos] = make_uint2(u.x & 0x1FFFFu, u.y);
    }
    __syncthreads();

    // accum: 4 waves x 16 nodes each
    const int lane = tid & 63;
    const int wv = tid >> 6;
    const int grp = lane >> 4;   // edge slot 0..3
    const int l16 = lane & 15;   // feats l16*8 .. +7

    float4 b0 = *reinterpret_cast<const float4*>(&bias[l16 * 8]);
    float4 b1 = *reinterpret_cast<const float4*>(&bias[l16 * 8 + 4]);

    for (int ni = 0; ni < 16; ++ni) {
        const int dl = wv * 16 + ni;
        const int node = b * FBUCK + dl;
        if (node >= N_NODES) break;
        const int s = (dl == 0) ? 0 : scanb[dl - 1];
        const int e = scanb[dl];

        float acc[8];
#pragma unroll
        for (int t = 0; t < 8; ++t) acc[t] = 0.f;

        int j = s + grp;
        for (; j + 4 < e; j += 8) {
            uint2 p0 = plds[j];
            uint2 p1 = plds[j + 4];
            uint4 s0 = *reinterpret_cast<const uint4*>(&support[(size_t)p0.x * OUT_F + l16 * 8]);
            uint4 s1 = *reinterpret_cast<const uint4*>(&support[(size_t)p1.x * OUT_F + l16 * 8]);
            float v0 = __uint_as_float(p0.y);
            float v1 = __uint_as_float(p1.y);
            unsigned u0[4] = {s0.x, s0.y, s0.z, s0.w};
            unsigned u1[4] = {s1.x, s1.y, s1.z, s1.w};
#pragma unroll
            for (int q = 0; q < 4; ++q) {
                acc[2 * q + 0] += __uint_as_float(u0[q] << 16) * v0;
                acc[2 * q + 1] += __uint_as_float(u0[q] & 0xffff0000u) * v0;
                acc[2 * q + 0] += __uint_as_float(u1[q] << 16) * v1;
                acc[2 * q + 1] += __uint_as_float(u1[q] & 0xffff0000u) * v1;
            }
        }
        for (; j < e; j += 4) {
            uint2 p0 = plds[j];
            uint4 s0 = *reinterpret_cast<const uint4*>(&support[(size_t)p0.x * OUT_F + l16 * 8]);
            float v0 = __uint_as_float(p0.y);
            unsigned u0[4] = {s0.x, s0.y, s0.z, s0.w};
#pragma unroll
            for (int q = 0; q < 4; ++q) {
                acc[2 * q + 0] += __uint_as_float(u0[q] << 16) * v0;
                acc[2 * q + 1] += __uint_as_float(u0[q] & 0xffff0000u) * v0;
            }
        }

#pragma unroll
        for (int t = 0; t < 8; ++t) {
            acc[t] += __shfl_xor(acc[t], 16);
            acc[t] += __shfl_xor(acc[t], 32);
        }

        if (grp == 0) {
            f32x4 o0 = {acc[0] + b0.x, acc[1] + b0.y, acc[2] + b0.z, acc[3] + b0.w};
            f32x4 o1 = {acc[4] + b1.x, acc[5] + b1.y, acc[6] + b1.z, acc[7] + b1.w};
            f32x4* op = reinterpret_cast<f32x4*>(&out[(size_t)node * OUT_F + l16 * 8]);
            __builtin_nontemporal_store(o0, op);
            __builtin_nontemporal_store(o1, op + 1);
        }
    }
}

extern "C" void kernel_launch(void* const* d_in, const int* in_sizes, int n_in,
                              void* d_out, int out_size, void* d_ws, size_t ws_size,
                              hipStream_t stream) {
    const float* x       = (const float*)d_in[0];
    const float* weight  = (const float*)d_in[1];
    const float* bias    = (const float*)d_in[2];
    const float* adj_val = (const float*)d_in[3];
    const int*   adj_row = (const int*)d_in[4];
    const int*   adj_col = (const int*)d_in[5];
    float* out = (float*)d_out;

    // workspace (~47 MB):
    //   support : 12.8M ushort (25.6 MB)
    //   wt      : 32768 ushort (64 KB)
    //   cursor  : 1564 int
    //   tmp     : NBUCK*CAP uint2 (20.8 MB)
    unsigned short* support = (unsigned short*)d_ws;
    unsigned short* wt = support + (size_t)N_NODES * OUT_F;
    int* cursor = (int*)(wt + IN_F * OUT_F);
    uint2* tmp = (uint2*)(cursor + 1564);

    // K1: weight transpose + zero bucket cursors
    wz_kernel<<<128 + 7, 256, 0, stream>>>(weight, wt, cursor);
    // K2: sort ∥ gemm
    gemm_sort_kernel<<<SORT_CHUNKS + GEMM_BLOCKS, 512, 0, stream>>>(
        x, wt, support, adj_row, adj_col, adj_val, cursor, tmp);
    // K3: fused fine-sort + accumulate per 64-node bucket
    fine_accum_kernel<<<NBUCK, 256, 0, stream>>>(support, tmp, cursor, bias, out);
}